// Round 4
// baseline (336.348 us; speedup 1.0000x reference)
//
#include <hip/hip_runtime.h>
#include <hip/hip_bf16.h>

#define N_NODES 50000
#define N_EDGES 800000
#define IN_CH 256
#define OUT_CH 64
#define NEG_BIG -9e15f
#define NBLK_E 3125   // N_EDGES / 256

// ---- ws layout (bytes), total ~16.5 MB ----
#define WS_WH    0          // fp32 [50000][64]  12,800,000
#define WS_E     12800000   // fp32 [800000]      3,200,000
#define WS_ESRC  16000000   // fp32 [50000]         200,000
#define WS_EDST  16200000   // fp32 [50000]         200,000
#define WS_BMAX  16400000   // fp32 [3125]
#define WS_BSUM  16416000   // fp32 [3125]
#define WS_M     16432000
#define WS_Z     16432004
#define WS_FLAGS 16432008   // int[2]: {edge_is_i64, float_is_f32}

// ---------- dtype-flexible loads ----------
__device__ __forceinline__ float loadf(const void* p, size_t i, int isf32) {
    return isf32 ? ((const float*)p)[i]
                 : __bfloat162float(((const __hip_bfloat16*)p)[i]);
}
__device__ __forceinline__ void load_edge(const int* __restrict__ ei, int i, int f64,
                                          int& s, int& d) {
    if (f64) { s = ei[2 * i]; d = ei[2 * (N_EDGES + i)]; }
    else     { s = ei[i];     d = ei[N_EDGES + i]; }
    s = min(max(s, 0), N_NODES - 1);
    d = min(max(d, 0), N_NODES - 1);
}

// ---------- K0: detect edge int64 and float fp32 ----------
__global__ __launch_bounds__(256) void k_flags(const int* __restrict__ ei,
                                               const unsigned* __restrict__ xw,
                                               int* __restrict__ flags) {
    int t = threadIdx.x;
    int v = 0;
    for (int i = t; i < 2048; i += 256) v |= ei[2 * i + 1];   // int64 high words == 0
    unsigned lo = xw[t] & 0xFFFFu;                            // sample 256 words of x
    unsigned e8 = (lo >> 7) & 0xFFu;
    int hit = (e8 >= 96u && e8 <= 144u) ? 1 : 0;              // bf16-packed: ~all hit
#pragma unroll
    for (int off = 32; off > 0; off >>= 1) {
        v |= __shfl_down(v, off);
        hit += __shfl_down(hit, off);
    }
    __shared__ int sv[4], sh[4];
    if ((t & 63) == 0) { sv[t >> 6] = v; sh[t >> 6] = hit; }
    __syncthreads();
    if (t == 0) {
        int allv = sv[0] | sv[1] | sv[2] | sv[3];
        int hits = sh[0] + sh[1] + sh[2] + sh[3];
        flags[0] = (allv == 0) ? 1 : 0;   // edge_index is int64
        flags[1] = (hits < 192) ? 1 : 0;  // floats are fp32
    }
}

// ---------- K1: wh = x @ W (fp32 out) + fused per-node logits ----------
__global__ __launch_bounds__(256) void k_mm(const void* __restrict__ xv,
                                            const void* __restrict__ Wv,
                                            const void* __restrict__ av,
                                            const int* __restrict__ flags,
                                            float* __restrict__ wh,
                                            float* __restrict__ esrc,
                                            float* __restrict__ edst) {
    int isf = flags[1];
    __shared__ float xs[4][IN_CH];
    int t = threadIdx.x;
    int nb = blockIdx.x * 4;
    for (int i = t; i < 4 * IN_CH; i += 256) {
        int r = i >> 8, k = i & 255;
        xs[r][k] = loadf(xv, (size_t)(nb + r) * IN_CH + k, isf);
    }
    __syncthreads();
    int c = t & 63, r = t >> 6;   // wave r -> node nb+r, lane c -> out channel
    float acc = 0.0f;
    if (isf) {
        const float* W = (const float*)Wv;
#pragma unroll 8
        for (int k = 0; k < IN_CH; ++k) acc += xs[r][k] * W[k * OUT_CH + c];
    } else {
        const __hip_bfloat16* W = (const __hip_bfloat16*)Wv;
#pragma unroll 8
        for (int k = 0; k < IN_CH; ++k) acc += xs[r][k] * __bfloat162float(W[k * OUT_CH + c]);
    }
    wh[(size_t)(nb + r) * OUT_CH + c] = acc;

    float s1 = acc * loadf(av, c, isf);
    float s2 = acc * loadf(av, OUT_CH + c, isf);
#pragma unroll
    for (int off = 32; off > 0; off >>= 1) {
        s1 += __shfl_down(s1, off);
        s2 += __shfl_down(s2, off);
    }
    if (c == 0) { esrc[nb + r] = s1; edst[nb + r] = s2; }
}

// ---------- K2: edge scores + per-block max ----------
__global__ __launch_bounds__(256) void k_edge(const int* __restrict__ ei,
                                              const int* __restrict__ flags,
                                              const float* __restrict__ esrc,
                                              const float* __restrict__ edst,
                                              float* __restrict__ e,
                                              float* __restrict__ bmax) {
    int f64 = flags[0];
    int i = blockIdx.x * 256 + threadIdx.x;
    int s, d;
    load_edge(ei, i, f64, s, d);
    float v = esrc[s] + edst[d];
    float ev = v > 0.0f ? v : NEG_BIG;   // leaky_relu + where(>0) collapse
    e[i] = ev;
    float mx = ev;
#pragma unroll
    for (int off = 32; off > 0; off >>= 1) mx = fmaxf(mx, __shfl_down(mx, off));
    __shared__ float sm[4];
    if ((threadIdx.x & 63) == 0) sm[threadIdx.x >> 6] = mx;
    __syncthreads();
    if (threadIdx.x == 0)
        bmax[blockIdx.x] = fmaxf(fmaxf(sm[0], sm[1]), fmaxf(sm[2], sm[3]));
}

// ---------- K3: reduce block maxes -> M ----------
__global__ __launch_bounds__(256) void k_rmax(const float* __restrict__ bmax,
                                              float* __restrict__ M) {
    float mx = NEG_BIG;
    for (int i = threadIdx.x; i < NBLK_E; i += 256) mx = fmaxf(mx, bmax[i]);
#pragma unroll
    for (int off = 32; off > 0; off >>= 1) mx = fmaxf(mx, __shfl_down(mx, off));
    __shared__ float sm[4];
    if ((threadIdx.x & 63) == 0) sm[threadIdx.x >> 6] = mx;
    __syncthreads();
    if (threadIdx.x == 0) *M = fmaxf(fmaxf(sm[0], sm[1]), fmaxf(sm[2], sm[3]));
}

// ---------- K4: e <- exp(e - M); per-block sum ----------
__global__ __launch_bounds__(256) void k_exp(float* __restrict__ e,
                                             const float* __restrict__ Mp,
                                             float* __restrict__ bsum) {
    float M = *Mp;
    int i = blockIdx.x * 256 + threadIdx.x;
    float t = expf(e[i] - M);
    e[i] = t;
#pragma unroll
    for (int off = 32; off > 0; off >>= 1) t += __shfl_down(t, off);
    __shared__ float sm[4];
    if ((threadIdx.x & 63) == 0) sm[threadIdx.x >> 6] = t;
    __syncthreads();
    if (threadIdx.x == 0) bsum[blockIdx.x] = sm[0] + sm[1] + sm[2] + sm[3];
}

// ---------- K5: reduce block sums -> Z ----------
__global__ __launch_bounds__(256) void k_rsum(const float* __restrict__ bsum,
                                              float* __restrict__ Z) {
    float s = 0.0f;
    for (int i = threadIdx.x; i < NBLK_E; i += 256) s += bsum[i];
#pragma unroll
    for (int off = 32; off > 0; off >>= 1) s += __shfl_down(s, off);
    __shared__ float sm[4];
    if ((threadIdx.x & 63) == 0) sm[threadIdx.x >> 6] = s;
    __syncthreads();
    if (threadIdx.x == 0) *Z = sm[0] + sm[1] + sm[2] + sm[3];
}

// ---------- K6: scatter messages into d_out (wave per edge, lane = channel) ----------
__global__ __launch_bounds__(256) void k_scatter(const int* __restrict__ ei,
                                                 const int* __restrict__ flags,
                                                 const float* __restrict__ e,
                                                 const float* __restrict__ Zp,
                                                 const float* __restrict__ wh,
                                                 float* __restrict__ hp) {
    int f64 = flags[0];
    float Z = *Zp;
    float invZ = (Z > 0.0f) ? 1.0f / Z : 0.0f;
    int wave = (blockIdx.x * 256 + (int)threadIdx.x) >> 6;
    int lane = threadIdx.x & 63;
    const int nwaves = (NBLK_E * 256) >> 6;   // 12500
    for (int i = wave; i < N_EDGES; i += nwaves) {
        float w = e[i] * invZ;
        if (w == 0.0f) continue;              // exp-underflow edges contribute nothing
        int s, d;
        load_edge(ei, i, f64, s, d);
        float msg = w * wh[(size_t)s * OUT_CH + lane];
        atomicAdd(&hp[(size_t)d * OUT_CH + lane], msg);
    }
}

// ---------- K7: in-place ELU on d_out ----------
__global__ __launch_bounds__(256) void k_elu(float* __restrict__ hp) {
    int i = blockIdx.x * 256 + threadIdx.x;
    float h = hp[i];
    hp[i] = h > 0.0f ? h : expf(h) - 1.0f;
}

extern "C" void kernel_launch(void* const* d_in, const int* in_sizes, int n_in,
                              void* d_out, int out_size, void* d_ws, size_t ws_size,
                              hipStream_t stream) {
    const void* x  = d_in[0];
    const int* ei  = (const int*)d_in[1];
    const void* W  = d_in[2];
    const void* a  = d_in[3];
    float* out     = (float*)d_out;   // reference output dtype is float32

    char* ws = (char*)d_ws;
    float* wh   = (float*)(ws + WS_WH);
    float* e    = (float*)(ws + WS_E);
    float* esrc = (float*)(ws + WS_ESRC);
    float* edst = (float*)(ws + WS_EDST);
    float* bmax = (float*)(ws + WS_BMAX);
    float* bsum = (float*)(ws + WS_BSUM);
    float* M    = (float*)(ws + WS_M);
    float* Z    = (float*)(ws + WS_Z);
    int*   flags= (int*)  (ws + WS_FLAGS);

    // h_prime accumulates directly in d_out (fp32 [50000][64])
    hipMemsetAsync(out, 0, (size_t)N_NODES * OUT_CH * sizeof(float), stream);

    k_flags  <<<1,           256, 0, stream>>>(ei, (const unsigned*)x, flags);
    k_mm     <<<N_NODES / 4, 256, 0, stream>>>(x, W, a, flags, wh, esrc, edst);
    k_edge   <<<NBLK_E,      256, 0, stream>>>(ei, flags, esrc, edst, e, bmax);
    k_rmax   <<<1,           256, 0, stream>>>(bmax, M);
    k_exp    <<<NBLK_E,      256, 0, stream>>>(e, M, bsum);
    k_rsum   <<<1,           256, 0, stream>>>(bsum, Z);
    k_scatter<<<NBLK_E,      256, 0, stream>>>(ei, flags, e, Z, wh, out);
    k_elu    <<<(N_NODES * OUT_CH) / 256, 256, 0, stream>>>(out);
}

// Round 5
// 279.477 us; speedup vs baseline: 1.2035x; 1.2035x over previous
//
#include <hip/hip_runtime.h>
#include <hip/hip_bf16.h>

#define N_NODES 50000
#define N_EDGES 800000
#define IN_CH 256
#define OUT_CH 64
#define NEG_BIG -9e15f
#define NBLK_E 3125   // N_EDGES / 256

typedef __bf16 bfvec8 __attribute__((ext_vector_type(8)));
typedef float floatx4 __attribute__((ext_vector_type(4)));

// ---- ws layout (bytes), total ~18.7 MB ----
#define WS_WHB   0          // bf16 [50000][64]   6,400,000
#define WS_E     6400000    // fp32 [800000]      3,200,000  raw scores
#define WS_W32   9600000    // fp32 [800000]      3,200,000  sorted exp weights
#define WS_PSRC  12800000   // u16  [800000]      1,600,000  sorted src
#define WS_SRC16 14400000   // u16  [800000]      1,600,000
#define WS_DST16 16000000   // u16  [800000]      1,600,000
#define WS_CNT   17600000   // int  [50000]
#define WS_ROWP  17800000   // int  [50000]
#define WS_WOFS  18000000   // int  [50000]
#define WS_WTH   18200000   // bf16 [64][256]        32,768
#define WS_WTL   18240000   // bf16 [64][256]        32,768
#define WS_ESRC  18280000   // fp32 [50000]
#define WS_EDST  18480000   // fp32 [50000]
#define WS_BMAX  18680000   // fp32 [3125]
#define WS_BSUM  18696000   // fp32 [3125]
#define WS_M     18712000
#define WS_Z     18712004
#define WS_FLAGS 18712008   // int[2]: {edge_is_i64, float_is_f32}

// ---------- dtype-flexible helpers ----------
__device__ __forceinline__ float loadf(const void* p, size_t i, int isf32) {
    return isf32 ? ((const float*)p)[i]
                 : __bfloat162float(((const __hip_bfloat16*)p)[i]);
}
__device__ __forceinline__ void load_edge(const int* __restrict__ ei, int i, int f64,
                                          int& s, int& d) {
    if (f64) { s = ei[2 * i]; d = ei[2 * (N_EDGES + i)]; }
    else     { s = ei[i];     d = ei[N_EDGES + i]; }
    s = min(max(s, 0), N_NODES - 1);
    d = min(max(d, 0), N_NODES - 1);
}

// ---------- K0: detect edge int64 and float fp32 ----------
__global__ __launch_bounds__(256) void k_flags(const int* __restrict__ ei,
                                               const unsigned* __restrict__ xw,
                                               int* __restrict__ flags) {
    int t = threadIdx.x;
    int v = 0;
    for (int i = t; i < 2048; i += 256) v |= ei[2 * i + 1];
    unsigned lo = xw[t] & 0xFFFFu;
    unsigned e8 = (lo >> 7) & 0xFFu;
    int hit = (e8 >= 96u && e8 <= 144u) ? 1 : 0;
#pragma unroll
    for (int off = 32; off > 0; off >>= 1) {
        v |= __shfl_down(v, off);
        hit += __shfl_down(hit, off);
    }
    __shared__ int sv[4], sh[4];
    if ((t & 63) == 0) { sv[t >> 6] = v; sh[t >> 6] = hit; }
    __syncthreads();
    if (t == 0) {
        flags[0] = ((sv[0] | sv[1] | sv[2] | sv[3]) == 0) ? 1 : 0;
        flags[1] = ((sh[0] + sh[1] + sh[2] + sh[3]) < 192) ? 1 : 0;
    }
}

// ---------- K1: Wt hi/lo split-transpose ----------
__global__ __launch_bounds__(256) void k_prep(const void* __restrict__ Wv,
                                              const int* __restrict__ flags,
                                              __bf16* __restrict__ Wth,
                                              __bf16* __restrict__ Wtl) {
    int isf = flags[1];
    int t = blockIdx.x * 256 + threadIdx.x;   // 0..16383
    int c = t >> 8, k = t & 255;
    float w = loadf(Wv, (size_t)k * OUT_CH + c, isf);
    __bf16 h = (__bf16)w;
    Wth[t] = h;
    Wtl[t] = (__bf16)(w - (float)h);
}

// ---------- K2: wh = x @ W via split-bf16 MFMA + fused fp32 logits ----------
// A[m][k]: m=lane&15, k=quad*8+j ; B[k][n]: n=lane&15, k=quad*8+j
// C/D: col(n)=lane&15, row(m)=quad*4+reg
__global__ __launch_bounds__(256) void k_mm(const void* __restrict__ xv,
                                            const __bf16* __restrict__ Wth,
                                            const __bf16* __restrict__ Wtl,
                                            const void* __restrict__ av,
                                            const int* __restrict__ flags,
                                            __bf16* __restrict__ whb,
                                            float* __restrict__ esrc,
                                            float* __restrict__ edst) {
    int isf = flags[1];
    int gw = (blockIdx.x * 256 + (int)threadIdx.x) >> 6;
    if (gw >= N_NODES / 16) return;           // wave-uniform
    int lane = threadIdx.x & 63;
    int m = lane & 15, quad = lane >> 4;
    int nb = gw * 16;

    floatx4 acc[4];
#pragma unroll
    for (int ct = 0; ct < 4; ++ct) acc[ct] = (floatx4){0.f, 0.f, 0.f, 0.f};

#pragma unroll
    for (int s = 0; s < 8; ++s) {
        int k0 = s * 32 + quad * 8;
        bfvec8 ahi, alo;
        if (isf) {
            const float* xr = (const float*)xv + (size_t)(nb + m) * IN_CH + k0;
            float v[8];
            *(floatx4*)(v)     = *(const floatx4*)(xr);
            *(floatx4*)(v + 4) = *(const floatx4*)(xr + 4);
#pragma unroll
            for (int j = 0; j < 8; ++j) {
                __bf16 h = (__bf16)v[j];
                ahi[j] = h;
                alo[j] = (__bf16)(v[j] - (float)h);
            }
        } else {
            ahi = *(const bfvec8*)((const __bf16*)xv + (size_t)(nb + m) * IN_CH + k0);
#pragma unroll
            for (int j = 0; j < 8; ++j) alo[j] = (__bf16)0.0f;
        }
#pragma unroll
        for (int ct = 0; ct < 4; ++ct) {
            bfvec8 bhi = *(const bfvec8*)(Wth + (ct * 16 + m) * IN_CH + k0);
            bfvec8 blo = *(const bfvec8*)(Wtl + (ct * 16 + m) * IN_CH + k0);
            acc[ct] = __builtin_amdgcn_mfma_f32_16x16x32_bf16(ahi, blo, acc[ct], 0, 0, 0);
            acc[ct] = __builtin_amdgcn_mfma_f32_16x16x32_bf16(alo, bhi, acc[ct], 0, 0, 0);
            acc[ct] = __builtin_amdgcn_mfma_f32_16x16x32_bf16(ahi, bhi, acc[ct], 0, 0, 0);
        }
    }

    float a1[4], a2[4];
#pragma unroll
    for (int ct = 0; ct < 4; ++ct) {
        a1[ct] = loadf(av, ct * 16 + m, isf);
        a2[ct] = loadf(av, OUT_CH + ct * 16 + m, isf);
    }
#pragma unroll
    for (int r = 0; r < 4; ++r) {
        int node = nb + quad * 4 + r;
        float s1 = 0.f, s2 = 0.f;
#pragma unroll
        for (int ct = 0; ct < 4; ++ct) {
            float vv = acc[ct][r];
            whb[(size_t)node * OUT_CH + ct * 16 + m] = (__bf16)vv;
            s1 += vv * a1[ct];
            s2 += vv * a2[ct];
        }
#pragma unroll
        for (int off = 1; off < 16; off <<= 1) {   // reduce over the 16 cols
            s1 += __shfl_xor(s1, off);
            s2 += __shfl_xor(s2, off);
        }
        if (m == 0) { esrc[node] = s1; edst[node] = s2; }
    }
}

// ---------- K3: raw scores + u16 idx + histogram(+filter) + block max ----------
__global__ __launch_bounds__(256) void k_edge(const int* __restrict__ ei,
                                              const int* __restrict__ flags,
                                              const float* __restrict__ esrc,
                                              const float* __restrict__ edst,
                                              float* __restrict__ e,
                                              unsigned short* __restrict__ src16,
                                              unsigned short* __restrict__ dst16,
                                              int* __restrict__ cnt,
                                              float* __restrict__ bmax) {
    int f64 = flags[0];
    int i = blockIdx.x * 256 + threadIdx.x;
    int s, d;
    load_edge(ei, i, f64, s, d);
    src16[i] = (unsigned short)s;
    dst16[i] = (unsigned short)d;
    float v = esrc[s] + edst[d];
    float ev = v > 0.0f ? v : NEG_BIG;
    e[i] = ev;
    if (ev > 0.0f) atomicAdd(&cnt[d], 1);
    float mx = ev;
#pragma unroll
    for (int off = 32; off > 0; off >>= 1) mx = fmaxf(mx, __shfl_down(mx, off));
    __shared__ float sm[4];
    if ((threadIdx.x & 63) == 0) sm[threadIdx.x >> 6] = mx;
    __syncthreads();
    if (threadIdx.x == 0)
        bmax[blockIdx.x] = fmaxf(fmaxf(sm[0], sm[1]), fmaxf(sm[2], sm[3]));
}

// ---------- K4: reduce block maxes -> M ----------
__global__ __launch_bounds__(256) void k_rmax(const float* __restrict__ bmax,
                                              float* __restrict__ M) {
    float mx = NEG_BIG;
    for (int i = threadIdx.x; i < NBLK_E; i += 256) mx = fmaxf(mx, bmax[i]);
#pragma unroll
    for (int off = 32; off > 0; off >>= 1) mx = fmaxf(mx, __shfl_down(mx, off));
    __shared__ float sm[4];
    if ((threadIdx.x & 63) == 0) sm[threadIdx.x >> 6] = mx;
    __syncthreads();
    if (threadIdx.x == 0) *M = fmaxf(fmaxf(sm[0], sm[1]), fmaxf(sm[2], sm[3]));
}

// ---------- K5: single-block exclusive scan of cnt -> rowptr, wofs ----------
__global__ __launch_bounds__(1024) void k_scan(const int* __restrict__ cnt,
                                               int* __restrict__ rowptr,
                                               int* __restrict__ wofs) {
    __shared__ int wsums[16];
    __shared__ int carry;
    int tid = threadIdx.x, lane = tid & 63, wid = tid >> 6;
    if (tid == 0) carry = 0;
    __syncthreads();
    for (int c = 0; c < 49; ++c) {
        int idx = c * 1024 + tid;
        int v = (idx < N_NODES) ? cnt[idx] : 0;
        int incl = v;
#pragma unroll
        for (int off = 1; off < 64; off <<= 1) {
            int t = __shfl_up(incl, off);
            if (lane >= off) incl += t;
        }
        if (lane == 63) wsums[wid] = incl;
        __syncthreads();
        if (wid == 0) {
            int wv = (lane < 16) ? wsums[lane] : 0;
            int wincl = wv;
#pragma unroll
            for (int off = 1; off < 16; off <<= 1) {
                int t = __shfl_up(wincl, off);
                if (lane >= off) wincl += t;
            }
            if (lane < 16) wsums[lane] = wincl;
        }
        __syncthreads();
        int wexcl = (wid == 0) ? 0 : wsums[wid - 1];
        int excl = carry + wexcl + (incl - v);
        if (idx < N_NODES) { rowptr[idx] = excl; wofs[idx] = excl; }
        int total = wsums[15];
        __syncthreads();                 // all reads of carry/wsums done
        if (tid == 0) carry += total;
        __syncthreads();
    }
}

// ---------- K6: exp + block sum + CSR placement ----------
__global__ __launch_bounds__(256) void k_exp(const float* __restrict__ e,
                                             const float* __restrict__ Mp,
                                             const unsigned short* __restrict__ src16,
                                             const unsigned short* __restrict__ dst16,
                                             int* __restrict__ wofs,
                                             float* __restrict__ w32,
                                             unsigned short* __restrict__ psrc,
                                             float* __restrict__ bsum) {
    float M = *Mp;
    int i = blockIdx.x * 256 + threadIdx.x;
    float ev = e[i];
    float t = expf(ev - M);          // masked edges: exp(-9e15-M) == 0
    if (ev > 0.0f) {
        int d = dst16[i];
        int pos = atomicAdd(&wofs[d], 1);
        w32[pos] = t;
        psrc[pos] = src16[i];
    }
#pragma unroll
    for (int off = 32; off > 0; off >>= 1) t += __shfl_down(t, off);
    __shared__ float sm[4];
    if ((threadIdx.x & 63) == 0) sm[threadIdx.x >> 6] = t;
    __syncthreads();
    if (threadIdx.x == 0) bsum[blockIdx.x] = sm[0] + sm[1] + sm[2] + sm[3];
}

// ---------- K7: reduce block sums -> Z ----------
__global__ __launch_bounds__(256) void k_rsum(const float* __restrict__ bsum,
                                              float* __restrict__ Z) {
    float s = 0.0f;
    for (int i = threadIdx.x; i < NBLK_E; i += 256) s += bsum[i];
#pragma unroll
    for (int off = 32; off > 0; off >>= 1) s += __shfl_down(s, off);
    __shared__ float sm[4];
    if ((threadIdx.x & 63) == 0) sm[threadIdx.x >> 6] = s;
    __syncthreads();
    if (threadIdx.x == 0) *Z = sm[0] + sm[1] + sm[2] + sm[3];
}

// ---------- K8: CSR gather, wave per dst node, lane = channel; fused ELU ----------
__global__ __launch_bounds__(256) void k_gather(const int* __restrict__ rowptr,
                                                const int* __restrict__ wofs,
                                                const float* __restrict__ w32,
                                                const unsigned short* __restrict__ psrc,
                                                const __bf16* __restrict__ whb,
                                                const float* __restrict__ Zp,
                                                float* __restrict__ out) {
    int gw = (blockIdx.x * 256 + (int)threadIdx.x) >> 6;   // dst node
    int c = threadIdx.x & 63;
    int beg = rowptr[gw];
    int end = wofs[gw];                                    // == rowptr+count after K6
    float Z = *Zp;
    float invZ = (Z > 0.0f) ? 1.0f / Z : 0.0f;
    float acc = 0.0f;
    for (int j = beg; j < end; ++j) {
        float t = w32[j];                                  // wave-uniform broadcast
        int s = psrc[j];
        acc += t * (float)whb[(size_t)s * OUT_CH + c];
    }
    float h = acc * invZ;
    out[(size_t)gw * OUT_CH + c] = h > 0.0f ? h : expf(h) - 1.0f;
}

extern "C" void kernel_launch(void* const* d_in, const int* in_sizes, int n_in,
                              void* d_out, int out_size, void* d_ws, size_t ws_size,
                              hipStream_t stream) {
    const void* x  = d_in[0];
    const int* ei  = (const int*)d_in[1];
    const void* W  = d_in[2];
    const void* a  = d_in[3];
    float* out     = (float*)d_out;

    char* ws = (char*)d_ws;
    __bf16* whb  = (__bf16*)(ws + WS_WHB);
    float* e     = (float*)(ws + WS_E);
    float* w32   = (float*)(ws + WS_W32);
    unsigned short* psrc  = (unsigned short*)(ws + WS_PSRC);
    unsigned short* src16 = (unsigned short*)(ws + WS_SRC16);
    unsigned short* dst16 = (unsigned short*)(ws + WS_DST16);
    int* cnt     = (int*)(ws + WS_CNT);
    int* rowptr  = (int*)(ws + WS_ROWP);
    int* wofs    = (int*)(ws + WS_WOFS);
    __bf16* Wth  = (__bf16*)(ws + WS_WTH);
    __bf16* Wtl  = (__bf16*)(ws + WS_WTL);
    float* esrc  = (float*)(ws + WS_ESRC);
    float* edst  = (float*)(ws + WS_EDST);
    float* bmax  = (float*)(ws + WS_BMAX);
    float* bsum  = (float*)(ws + WS_BSUM);
    float* M     = (float*)(ws + WS_M);
    float* Z     = (float*)(ws + WS_Z);
    int*   flags = (int*)(ws + WS_FLAGS);

    hipMemsetAsync(cnt, 0, N_NODES * sizeof(int), stream);

    k_flags <<<1,    256, 0, stream>>>(ei, (const unsigned*)x, flags);
    k_prep  <<<64,   256, 0, stream>>>(W, flags, Wth, Wtl);
    k_mm    <<<782,  256, 0, stream>>>(x, Wth, Wtl, a, flags, whb, esrc, edst);
    k_edge  <<<NBLK_E, 256, 0, stream>>>(ei, flags, esrc, edst, e, src16, dst16, cnt, bmax);
    k_rmax  <<<1,    256, 0, stream>>>(bmax, M);
    k_scan  <<<1,   1024, 0, stream>>>(cnt, rowptr, wofs);
    k_exp   <<<NBLK_E, 256, 0, stream>>>(e, M, src16, dst16, wofs, w32, psrc, bsum);
    k_rsum  <<<1,    256, 0, stream>>>(bsum, Z);
    k_gather<<<N_NODES / 4, 256, 0, stream>>>(rowptr, wofs, w32, psrc, whb, Z, out);
}